// Round 4
// baseline (3579.047 us; speedup 1.0000x reference)
//
#include <hip/hip_runtime.h>
#include <stdint.h>

#define Bv 64
#define Tv 2048
#define Iv 128
#define Hv 512
#define Ov 64

typedef _Float16 half_t;
typedef _Float16 half2_t __attribute__((ext_vector_type(2)));

__device__ __forceinline__ float fdot2(unsigned int a, unsigned int b, float c) {
#if __has_builtin(__builtin_amdgcn_fdot2)
    return __builtin_amdgcn_fdot2(__builtin_bit_cast(half2_t, a),
                                  __builtin_bit_cast(half2_t, b), c, false);
#else
    half2_t ha = __builtin_bit_cast(half2_t, a);
    half2_t hb = __builtin_bit_cast(half2_t, b);
    return c + (float)ha.x * (float)hb.x + (float)ha.y * (float)hb.y;
#endif
}

__device__ __forceinline__ unsigned int pack2(float a, float b) {
    half2_t v; v.x = (half_t)a; v.y = (half_t)b;
    return __builtin_bit_cast(unsigned int, v);
}

// ===================== FAST PATH =====================
// wrec row k-range split: [0,336) -> pinned registers (168 uints),
// [336,360) -> free registers (12 uints, compiler may remat from L2),
// [360,512) -> LDS (19 uint4 groups)

// wrA[m][j] (m<180, j<512): half2(wrec[j][2m], wrec[j][2m+1])
__global__ void pack_wrA_k(const float* __restrict__ wrec, unsigned int* __restrict__ wp) {
    int idx = blockIdx.x * 256 + threadIdx.x;
    if (idx >= 180 * 512) return;
    int j = idx & 511, m = idx >> 9;
    wp[idx] = pack2(wrec[j * Hv + 2 * m], wrec[j * Hv + 2 * m + 1]);
}

// wB[g][j][c] (g<19, j<512, c<4): half2(wrec[j][360+8g+2c], wrec[j][360+8g+2c+1])
__global__ void pack_wB_k(const float* __restrict__ wrec, unsigned int* __restrict__ wp) {
    int idx = blockIdx.x * 256 + threadIdx.x;
    if (idx >= 19 * 512 * 4) return;
    int c = idx & 3, j = (idx >> 2) & 511, g = idx >> 11;
    int k = 360 + 8 * g + 2 * c;
    wp[idx] = pack2(wrec[j * Hv + k], wrec[j * Hv + k + 1]);
}

// wip[m][j] (m<64, j<512): half2(wi[2m][j], wi[2m+1][j])
__global__ void pack_wip_k(const float* __restrict__ wi, unsigned int* __restrict__ wp) {
    int idx = blockIdx.x * 256 + threadIdx.x;
    int j = idx & 511, m = idx >> 9;
    wp[idx] = pack2(wi[(2 * m) * Hv + j], wi[(2 * m + 1) * Hv + j]);
}

// wop4[g][o] (g<64, o<64): uint4 of half2 pairs of wout rows 8g..8g+7, col o
__global__ void pack_wop_k(const float* __restrict__ wout, uint4* __restrict__ wp) {
    int idx = blockIdx.x * 256 + threadIdx.x;
    if (idx >= 64 * 64) return;
    int o = idx & 63, g = idx >> 6;
    uint4 v;
    v.x = pack2(wout[(8 * g + 0) * Ov + o], wout[(8 * g + 1) * Ov + o]);
    v.y = pack2(wout[(8 * g + 2) * Ov + o], wout[(8 * g + 3) * Ov + o]);
    v.z = pack2(wout[(8 * g + 4) * Ov + o], wout[(8 * g + 5) * Ov + o]);
    v.w = pack2(wout[(8 * g + 6) * Ov + o], wout[(8 * g + 7) * Ov + o]);
    wp[idx] = v;
}

// z[bt][j] = 0.1 * sum_i x[bt][i]*wi[i][j] + 0.0005 * noise[bt][j], f16.
__global__ __launch_bounds__(512) void z_kernel(
    const float* __restrict__ x, const float* __restrict__ noise,
    const unsigned int* __restrict__ wip, half_t* __restrict__ zg)
{
    __shared__ uint4 xs[32 * 16];
    const int tid = threadIdx.x;
    const size_t bt0 = (size_t)blockIdx.x * 32;

    unsigned int wiR[64];
#pragma unroll
    for (int m = 0; m < 64; ++m) wiR[m] = wip[m * 512 + tid];

    for (int idx = tid; idx < 32 * 64; idx += 512) {
        int row = idx >> 6, m = idx & 63;
        float2 xv = ((const float2*)x)[(bt0 + row) * 64 + m];
        ((unsigned int*)xs)[idx] = pack2(xv.x, xv.y);
    }
    __syncthreads();

    for (int row = 0; row < 32; ++row) {
        float a0 = 0.f, a1 = 0.f, a2 = 0.f, a3 = 0.f;
#pragma unroll
        for (int g = 0; g < 16; ++g) {
            uint4 xv = xs[row * 16 + g];
            a0 = fdot2(wiR[4 * g + 0], xv.x, a0);
            a1 = fdot2(wiR[4 * g + 1], xv.y, a1);
            a2 = fdot2(wiR[4 * g + 2], xv.z, a2);
            a3 = fdot2(wiR[4 * g + 3], xv.w, a3);
        }
        float nv = noise[(bt0 + row) * 512 + tid];
        zg[(bt0 + row) * 512 + tid] = (half_t)(0.1f * ((a0 + a1) + (a2 + a3)) + 0.0005f * nv);
    }
}

// Persistent scan: 1 WG/batch, 512 threads, wrec in regs+LDS, r via LDS ping-pong.
// R3 post-mortem: wrA loads are invariant -> LLVM remats them in-loop at zero
// modeled cost, so VGPR stays ~112 regardless of waves_per_eu. The empty
// asm "+v" makes each weight an asm-defined value: not rematerializable, so the
// allocator must keep it resident (budget 256 at 2 waves/SIMD) or scratch-spill.
__global__ __attribute__((amdgpu_flat_work_group_size(512, 512), amdgpu_waves_per_eu(2, 2)))
void rnn_fast(
    const unsigned int* __restrict__ wrAg,   // [180][512]
    const uint4* __restrict__ wBg,           // [19][512]
    const half_t* __restrict__ zg,           // [B][T][512]
    const float* __restrict__ h0,
    half_t* __restrict__ rstore)             // [B][T][512]
{
    extern __shared__ unsigned char smem[];
    uint4* wlds = (uint4*)smem;                                   // 155648 B
    half_t* s_r16 = (half_t*)(smem + 19 * 512 * 16);              // [2][512] f16
    const uint4* s_r4 = (const uint4*)s_r16;

    const int tid = threadIdx.x;
    const int b = blockIdx.x;

    for (int i = tid; i < 19 * 512; i += 512) wlds[i] = wBg[i];

    // pinned register weights: k in [0,336)
    unsigned int wrA[168];
#pragma unroll
    for (int m = 0; m < 168; ++m) wrA[m] = wrAg[m * 512 + tid];
#pragma unroll
    for (int m = 0; m < 168; ++m) asm volatile("" : "+v"(wrA[m]));

    // free-floating weights: k in [336,360) — compiler may keep or remat (24KB/step L2)
    unsigned int wrF[12];
#pragma unroll
    for (int m = 0; m < 12; ++m) wrF[m] = wrAg[(168 + m) * 512 + tid];

    const half_t* zb = zg + (size_t)b * Tv * Hv;
    half_t* rb = rstore + (size_t)b * Tv * Hv;

    float h = h0[tid];
    half_t r0 = (half_t)tanhf(h);
    s_r16[tid] = r0;
    rb[tid] = r0;
    half_t zpf = zb[tid];
    __syncthreads();

    int cur = 0;
    for (int t = 0; t < Tv - 1; ++t) {
        half_t zc = zpf;
        zpf = zb[(size_t)(t + 1) * Hv + tid];

        const uint4* rq = s_r4 + cur * 64;
        float a0 = 0.f, a1 = 0.f, a2 = 0.f, a3 = 0.f;
#pragma unroll
        for (int q = 0; q < 42; ++q) {           // k in [0,336): pinned registers
            uint4 rv = rq[q];                    // LDS broadcast
            a0 = fdot2(wrA[4 * q + 0], rv.x, a0);
            a1 = fdot2(wrA[4 * q + 1], rv.y, a1);
            a2 = fdot2(wrA[4 * q + 2], rv.z, a2);
            a3 = fdot2(wrA[4 * q + 3], rv.w, a3);
        }
#pragma unroll
        for (int q = 0; q < 3; ++q) {            // k in [336,360): free registers
            uint4 rv = rq[42 + q];
            a0 = fdot2(wrF[4 * q + 0], rv.x, a0);
            a1 = fdot2(wrF[4 * q + 1], rv.y, a1);
            a2 = fdot2(wrF[4 * q + 2], rv.z, a2);
            a3 = fdot2(wrF[4 * q + 3], rv.w, a3);
        }
#pragma unroll
        for (int g = 0; g < 19; ++g) {           // k in [360,512): LDS weights
            uint4 rv = rq[45 + g];
            uint4 wv = wlds[g * 512 + tid];
            a0 = fdot2(wv.x, rv.x, a0);
            a1 = fdot2(wv.y, rv.y, a1);
            a2 = fdot2(wv.z, rv.z, a2);
            a3 = fdot2(wv.w, rv.w, a3);
        }
        float acc = (a0 + a1) + (a2 + a3);
        h = 0.9f * h + 0.1f * acc + (float)zc;
        half_t r = (half_t)tanhf(h);
        s_r16[(cur ^ 1) * 512 + tid] = r;
        rb[(size_t)(t + 1) * Hv + tid] = r;
        __syncthreads();
        cur ^= 1;
    }
}

// out[bt][o] = sum_j r[bt][j] * wout[j][o]
__global__ __launch_bounds__(256) void out_kernel(
    const half_t* __restrict__ rstore, const uint4* __restrict__ wop4, float* __restrict__ out)
{
    __shared__ uint4 rr[32 * 64];
    const int tid = threadIdx.x;
    const int o = tid & 63, q = tid >> 6;
    const size_t bt0 = (size_t)blockIdx.x * 32;

    for (int idx = tid; idx < 32 * 64; idx += 256)
        rr[idx] = ((const uint4*)rstore)[bt0 * 64 + idx];
    __syncthreads();

    float acc[8] = {0.f, 0.f, 0.f, 0.f, 0.f, 0.f, 0.f, 0.f};
#pragma unroll 8
    for (int g = 0; g < 64; ++g) {
        uint4 wv = wop4[g * 64 + o];
#pragma unroll
        for (int i = 0; i < 8; ++i) {
            uint4 rv = rr[(q + 4 * i) * 64 + g];
            float a = fdot2(wv.x, rv.x, acc[i]);
            a = fdot2(wv.y, rv.y, a);
            a = fdot2(wv.z, rv.z, a);
            acc[i] = fdot2(wv.w, rv.w, a);
        }
    }
#pragma unroll
    for (int i = 0; i < 8; ++i)
        out[(bt0 + q + 4 * i) * Ov + o] = acc[i];
}

// ===================== LEGACY FALLBACK (R1, proven) =====================
__global__ void pack_wrec_k(const float* __restrict__ wrec, unsigned int* __restrict__ wp) {
    int tid = blockIdx.x * 256 + threadIdx.x;
    int k = tid & 3, j = (tid >> 2) & 511, q = tid >> 11;
    int i0 = 8 * q + 2 * k;
    wp[tid] = pack2(wrec[j * Hv + i0], wrec[j * Hv + i0 + 1]);
}
__global__ void pack_wi_k(const float* __restrict__ wi, unsigned int* __restrict__ wp) {
    int tid = blockIdx.x * 256 + threadIdx.x;
    int k = tid & 3, j = (tid >> 2) & 511, q = tid >> 11;
    int i0 = 8 * q + 2 * k;
    wp[tid] = pack2(wi[i0 * Hv + j], wi[(i0 + 1) * Hv + j]);
}
__global__ void pack_wout_k(const float* __restrict__ wout, unsigned int* __restrict__ wp) {
    int tid = blockIdx.x * 256 + threadIdx.x;
    int o = tid & 63, m = tid >> 6;
    wp[tid] = pack2(wout[(2 * m) * Ov + o], wout[(2 * m + 1) * Ov + o]);
}
__global__ __launch_bounds__(512) void rnn_persistent(
    const float* __restrict__ x, const float* __restrict__ noise,
    const float* __restrict__ h0,
    const unsigned int* __restrict__ wrecp,
    const unsigned int* __restrict__ wip,
    const unsigned int* __restrict__ wop,
    float* __restrict__ out)
{
    __shared__ __align__(16) unsigned int s_r[2][256];
    __shared__ __align__(16) unsigned int s_x[64];
    const int tid = threadIdx.x;
    const int b = blockIdx.x;
    const int o = tid >> 3;
    const int g = tid & 7;
    const float* xb = x + (size_t)b * Tv * Iv;
    const float* nb = noise + (size_t)b * Tv * Hv;
    float* ob = out + (size_t)b * Tv * Ov;
    unsigned int wiReg[64];
#pragma unroll
    for (int m = 0; m < 64; ++m)
        wiReg[m] = wip[(((m >> 2) * Hv) + tid) * 4 + (m & 3)];
    unsigned int wo[32];
#pragma unroll
    for (int k = 0; k < 32; ++k)
        wo[k] = wop[(g * 32 + k) * Ov + o];
    float h = h0[tid];
    ((half_t*)&s_r[0][0])[tid] = (half_t)tanhf(h);
    __syncthreads();
    {
        float po = 0.f;
        const uint4* r2 = (const uint4*)&s_r[0][0];
#pragma unroll
        for (int k = 0; k < 8; ++k) {
            uint4 rv = r2[g * 8 + k];
            po = fdot2(wo[4 * k + 0], rv.x, po);
            po = fdot2(wo[4 * k + 1], rv.y, po);
            po = fdot2(wo[4 * k + 2], rv.z, po);
            po = fdot2(wo[4 * k + 3], rv.w, po);
        }
        po += __shfl_xor(po, 1, 64);
        po += __shfl_xor(po, 2, 64);
        po += __shfl_xor(po, 4, 64);
        if (g == 0) ob[o] = po;
    }
    const uint4* wr4 = (const uint4*)wrecp;
    int cur = 0;
    for (int t = 0; t < Tv - 1; ++t) {
        const int nxt = cur ^ 1;
        float nval = nb[t * Hv + tid];
        if (tid < Iv) ((half_t*)&s_x[0])[tid] = (half_t)xb[t * Iv + tid];
        __syncthreads();
        float acc = 0.f;
        const uint4* rr4 = (const uint4*)&s_r[cur][0];
#pragma unroll 8
        for (int q = 0; q < 64; ++q) {
            uint4 w = wr4[q * Hv + tid];
            uint4 r = rr4[q];
            acc = fdot2(w.x, r.x, acc);
            acc = fdot2(w.y, r.y, acc);
            acc = fdot2(w.z, r.z, acc);
            acc = fdot2(w.w, r.w, acc);
        }
        const uint4* xx4 = (const uint4*)&s_x[0];
#pragma unroll
        for (int m = 0; m < 16; ++m) {
            uint4 xv = xx4[m];
            acc = fdot2(wiReg[4 * m + 0], xv.x, acc);
            acc = fdot2(wiReg[4 * m + 1], xv.y, acc);
            acc = fdot2(wiReg[4 * m + 2], xv.z, acc);
            acc = fdot2(wiReg[4 * m + 3], xv.w, acc);
        }
        h = h + 0.0005f * nval + 0.1f * (acc - h);
        ((half_t*)&s_r[nxt][0])[tid] = (half_t)tanhf(h);
        __syncthreads();
        float po = 0.f;
        const uint4* r2 = (const uint4*)&s_r[nxt][0];
#pragma unroll
        for (int k = 0; k < 8; ++k) {
            uint4 rv = r2[g * 8 + k];
            po = fdot2(wo[4 * k + 0], rv.x, po);
            po = fdot2(wo[4 * k + 1], rv.y, po);
            po = fdot2(wo[4 * k + 2], rv.z, po);
            po = fdot2(wo[4 * k + 3], rv.w, po);
        }
        po += __shfl_xor(po, 1, 64);
        po += __shfl_xor(po, 2, 64);
        po += __shfl_xor(po, 4, 64);
        if (g == 0) ob[(t + 1) * Ov + o] = po;
        cur = nxt;
    }
}

// ===================== LAUNCHER =====================
extern "C" void kernel_launch(void* const* d_in, const int* in_sizes, int n_in,
                              void* d_out, int out_size, void* d_ws, size_t ws_size,
                              hipStream_t stream) {
    const float* input = (const float*)d_in[0];
    const float* noise = (const float*)d_in[1];
    const float* wi    = (const float*)d_in[2];
    const float* wrec  = (const float*)d_in[3];
    const float* wout  = (const float*)d_in[4];
    const float* h0    = (const float*)d_in[5];
    float* out = (float*)d_out;

    const size_t Z_OFF  = 0;
    const size_t R_OFF  = Z_OFF + 134217728;
    const size_t WA_OFF = R_OFF + 134217728;
    const size_t WB_OFF = WA_OFF + 368640;
    const size_t WI_OFF = WB_OFF + 155648;
    const size_t WO_OFF = WI_OFF + 131072;
    const size_t NEED   = WO_OFF + 65536;

    if (ws_size >= NEED) {
        unsigned char* ws = (unsigned char*)d_ws;
        half_t*       zg    = (half_t*)(ws + Z_OFF);
        half_t*       rsg   = (half_t*)(ws + R_OFF);
        unsigned int* wrAg  = (unsigned int*)(ws + WA_OFF);
        unsigned int* wBg   = (unsigned int*)(ws + WB_OFF);
        unsigned int* wipg  = (unsigned int*)(ws + WI_OFF);
        uint4*        wop4g = (uint4*)(ws + WO_OFF);

        hipLaunchKernelGGL(pack_wrA_k, dim3(360), dim3(256), 0, stream, wrec, wrAg);
        hipLaunchKernelGGL(pack_wB_k,  dim3(152), dim3(256), 0, stream, wrec, wBg);
        hipLaunchKernelGGL(pack_wip_k, dim3(128), dim3(256), 0, stream, wi, wipg);
        hipLaunchKernelGGL(pack_wop_k, dim3(16),  dim3(256), 0, stream, wout, wop4g);

        hipLaunchKernelGGL(z_kernel, dim3((Bv * Tv) / 32), dim3(512), 0, stream,
                           input, noise, wipg, zg);

        const int smem = 19 * 512 * 16 + 2 * 512 * 2;   // 157696 B
        hipFuncSetAttribute((const void*)rnn_fast,
                            hipFuncAttributeMaxDynamicSharedMemorySize, smem);
        hipLaunchKernelGGL(rnn_fast, dim3(Bv), dim3(512), smem, stream,
                           wrAg, (const uint4*)wBg, zg, h0, rsg);

        hipLaunchKernelGGL(out_kernel, dim3((Bv * Tv) / 32), dim3(256), 0, stream,
                           rsg, wop4g, out);
    } else {
        unsigned int* wrecp = (unsigned int*)d_ws;
        unsigned int* wip   = wrecp + 64 * 512 * 4;
        unsigned int* wop   = wip   + 16 * 512 * 4;
        hipLaunchKernelGGL(pack_wrec_k, dim3(512), dim3(256), 0, stream, wrec, wrecp);
        hipLaunchKernelGGL(pack_wi_k,   dim3(128), dim3(256), 0, stream, wi, wip);
        hipLaunchKernelGGL(pack_wout_k, dim3(64),  dim3(256), 0, stream, wout, wop);
        hipLaunchKernelGGL(rnn_persistent, dim3(Bv), dim3(512), 0, stream,
                           input, noise, h0, wrecp, wip, wop, out);
    }
}

// Round 6
// 3485.443 us; speedup vs baseline: 1.0269x; 1.0269x over previous
//
#include <hip/hip_runtime.h>
#include <stdint.h>

#define Bv 64
#define Tv 2048
#define Iv 128
#define Hv 512
#define Ov 64

typedef _Float16 half_t;
typedef _Float16 half2_t __attribute__((ext_vector_type(2)));

__device__ __forceinline__ float fdot2(unsigned int a, unsigned int b, float c) {
#if __has_builtin(__builtin_amdgcn_fdot2)
    return __builtin_amdgcn_fdot2(__builtin_bit_cast(half2_t, a),
                                  __builtin_bit_cast(half2_t, b), c, false);
#else
    half2_t ha = __builtin_bit_cast(half2_t, a);
    half2_t hb = __builtin_bit_cast(half2_t, b);
    return c + (float)ha.x * (float)hb.x + (float)ha.y * (float)hb.y;
#endif
}

__device__ __forceinline__ unsigned int pack2(float a, float b) {
    half2_t v; v.x = (half_t)a; v.y = (half_t)b;
    return __builtin_bit_cast(unsigned int, v);
}

// ===================== FAST PATH (S=4 k-sliced) =====================
// Thread tid: w=tid>>6, l=tid&63, s=l>>4, u=l&15.
// Handles outputs j_p = 64w+u+16p (p<4) over k-slice [128s,128s+128).
// Per (output,slice): 64 k-pairs; m in [0,45) -> registers, m in [45,64) -> LDS.

// wrA4[row][tid], row = 45p+m (row<180): pack2(wrec[j_p][128s+2m], +1)
__global__ void pack_wrA4_k(const float* __restrict__ wrec, unsigned int* __restrict__ wp) {
    int idx = blockIdx.x * 256 + threadIdx.x;
    if (idx >= 180 * 512) return;
    int tid = idx & 511, row = idx >> 9;
    int p = row / 45, m = row % 45;
    int w = tid >> 6, lm = tid & 63, s = lm >> 4, u = lm & 15;
    int j = 64 * w + u + 16 * p;
    int k0 = 128 * s + 2 * m;
    wp[idx] = pack2(wrec[j * Hv + k0], wrec[j * Hv + k0 + 1]);
}

// wB4[g][tid][c] (g<19, c=output p): pair m=45+g of output j_c, k-slice s.
__global__ void pack_wB4_k(const float* __restrict__ wrec, unsigned int* __restrict__ wp) {
    int idx = blockIdx.x * 256 + threadIdx.x;
    if (idx >= 19 * 512 * 4) return;
    int c = idx & 3, tid = (idx >> 2) & 511, g = idx >> 11;
    int w = tid >> 6, lm = tid & 63, s = lm >> 4, u = lm & 15;
    int j = 64 * w + u + 16 * c;
    int m = 45 + g;
    int k0 = 128 * s + 2 * m;
    wp[idx] = pack2(wrec[j * Hv + k0], wrec[j * Hv + k0 + 1]);
}

// wip[m][j] (m<64, j<512): half2(wi[2m][j], wi[2m+1][j])
__global__ void pack_wip_k(const float* __restrict__ wi, unsigned int* __restrict__ wp) {
    int idx = blockIdx.x * 256 + threadIdx.x;
    int j = idx & 511, m = idx >> 9;
    wp[idx] = pack2(wi[(2 * m) * Hv + j], wi[(2 * m + 1) * Hv + j]);
}

// wop4[g][o] (g<64, o<64): uint4 of half2 pairs of wout rows 8g..8g+7, col o
__global__ void pack_wop_k(const float* __restrict__ wout, uint4* __restrict__ wp) {
    int idx = blockIdx.x * 256 + threadIdx.x;
    if (idx >= 64 * 64) return;
    int o = idx & 63, g = idx >> 6;
    uint4 v;
    v.x = pack2(wout[(8 * g + 0) * Ov + o], wout[(8 * g + 1) * Ov + o]);
    v.y = pack2(wout[(8 * g + 2) * Ov + o], wout[(8 * g + 3) * Ov + o]);
    v.z = pack2(wout[(8 * g + 4) * Ov + o], wout[(8 * g + 5) * Ov + o]);
    v.w = pack2(wout[(8 * g + 6) * Ov + o], wout[(8 * g + 7) * Ov + o]);
    wp[idx] = v;
}

// z[bt][j] = 0.1 * sum_i x[bt][i]*wi[i][j] + 0.0005 * noise[bt][j], f16.
__global__ __launch_bounds__(512) void z_kernel(
    const float* __restrict__ x, const float* __restrict__ noise,
    const unsigned int* __restrict__ wip, half_t* __restrict__ zg)
{
    __shared__ uint4 xs[32 * 16];
    const int tid = threadIdx.x;
    const size_t bt0 = (size_t)blockIdx.x * 32;

    unsigned int wiR[64];
#pragma unroll
    for (int m = 0; m < 64; ++m) wiR[m] = wip[m * 512 + tid];

    for (int idx = tid; idx < 32 * 64; idx += 512) {
        int row = idx >> 6, m = idx & 63;
        float2 xv = ((const float2*)x)[(bt0 + row) * 64 + m];
        ((unsigned int*)xs)[idx] = pack2(xv.x, xv.y);
    }
    __syncthreads();

    for (int row = 0; row < 32; ++row) {
        float a0 = 0.f, a1 = 0.f, a2 = 0.f, a3 = 0.f;
#pragma unroll
        for (int g = 0; g < 16; ++g) {
            uint4 xv = xs[row * 16 + g];
            a0 = fdot2(wiR[4 * g + 0], xv.x, a0);
            a1 = fdot2(wiR[4 * g + 1], xv.y, a1);
            a2 = fdot2(wiR[4 * g + 2], xv.z, a2);
            a3 = fdot2(wiR[4 * g + 3], xv.w, a3);
        }
        float nv = noise[(bt0 + row) * 512 + tid];
        zg[(bt0 + row) * 512 + tid] = (half_t)(0.1f * ((a0 + a1) + (a2 + a3)) + 0.0005f * nv);
    }
}

// r element j at byte: q*1088 + (j>>7)*272 + (j&127)*2   (16B skew per 128-slice)
#define RSKEW(q, j) ((q) * 1088 + ((j) >> 7) * 272 + ((j) & 127) * 2)

// 4 reg-weight dot2s against one r-uint RU at pair m=M (outputs p=0..3)
#define STEP_REG(RU, M)                                   \
    acc0 = fdot2(wrA[(M)], (RU), acc0);                   \
    acc1 = fdot2(wrA[45 + (M)], (RU), acc1);              \
    acc2 = fdot2(wrA[90 + (M)], (RU), acc2);              \
    acc3 = fdot2(wrA[135 + (M)], (RU), acc3);

// 4 LDS-weight dot2s: uint4 from wlds[(M-45)*512+tid], components = outputs
#define STEP_LDS(RU, M)                                   \
    {                                                     \
        uint4 wv = wlds[((M) - 45) * 512 + tid];          \
        acc0 = fdot2(wv.x, (RU), acc0);                   \
        acc1 = fdot2(wv.y, (RU), acc1);                   \
        acc2 = fdot2(wv.z, (RU), acc2);                   \
        acc3 = fdot2(wv.w, (RU), acc3);                   \
    }

__global__ __attribute__((amdgpu_flat_work_group_size(512, 512), amdgpu_waves_per_eu(2, 2)))
void rnn_fast(
    const unsigned int* __restrict__ wrAg,   // [180][512]
    const uint4* __restrict__ wBg,           // [19*512] uint4
    const half_t* __restrict__ zg,           // [B][T][512]
    const float* __restrict__ h0,
    half_t* __restrict__ rstore)             // [B][T][512]
{
    extern __shared__ unsigned char smem[];
    uint4* wlds = (uint4*)smem;                         // 19*512*16 = 155648 B
    unsigned char* rbase = smem + 19 * 512 * 16;        // 2*1088 = 2176 B skewed r

    const int tid = threadIdx.x;
    const int b = blockIdx.x;
    const int s = (tid >> 4) & 3;
    const int jown = ((tid >> 6) << 6) + (tid & 15) + 16 * s;   // 64w + u + 16s

    for (int i = tid; i < 19 * 512; i += 512) wlds[i] = wBg[i];

    // register weights: rows 45p+m, m in [0,45)
    unsigned int wrA[180];
#pragma unroll
    for (int m = 0; m < 180; ++m) wrA[m] = wrAg[m * 512 + tid];
    asm volatile("" ::: "memory");   // forbid remat of the weight loads inside the loop

    const half_t* zb = zg + (size_t)b * Tv * Hv;
    half_t* rb = rstore + (size_t)b * Tv * Hv;

    float h = h0[jown];
    half_t r0 = (half_t)tanhf(h);
    *(half_t*)(rbase + RSKEW(0, jown)) = r0;
    rb[jown] = r0;
    half_t zpf = zb[jown];
    __syncthreads();

    int cur = 0;
    for (int t = 0; t < Tv - 1; ++t) {
        half_t zc = zpf;
        zpf = zb[(size_t)(t + 1) * Hv + jown];

        // this thread's 128-element r-slice (16 uint4, 4-addr broadcast, bank-skewed)
        const uint4* rq = (const uint4*)(rbase + cur * 1088 + s * 272);

        float acc0 = 0.f, acc1 = 0.f, acc2 = 0.f, acc3 = 0.f;
#pragma unroll
        for (int g = 0; g < 11; ++g) {           // pairs 0..43: all-register
            uint4 rv = rq[g];
            STEP_REG(rv.x, 4 * g + 0)
            STEP_REG(rv.y, 4 * g + 1)
            STEP_REG(rv.z, 4 * g + 2)
            STEP_REG(rv.w, 4 * g + 3)
        }
        {                                        // pairs 44 (reg) + 45..47 (LDS)
            uint4 rv = rq[11];
            STEP_REG(rv.x, 44)
            STEP_LDS(rv.y, 45)
            STEP_LDS(rv.z, 46)
            STEP_LDS(rv.w, 47)
        }
#pragma unroll
        for (int g = 12; g < 16; ++g) {          // pairs 48..63: LDS
            uint4 rv = rq[g];
            STEP_LDS(rv.x, 4 * g + 0)
            STEP_LDS(rv.y, 4 * g + 1)
            STEP_LDS(rv.z, 4 * g + 2)
            STEP_LDS(rv.w, 4 * g + 3)
        }

        // butterfly-reduce the 4 slice-partials across lane groups (xor16, xor32)
        acc0 += __shfl_xor(acc0, 16, 64); acc0 += __shfl_xor(acc0, 32, 64);
        acc1 += __shfl_xor(acc1, 16, 64); acc1 += __shfl_xor(acc1, 32, 64);
        acc2 += __shfl_xor(acc2, 16, 64); acc2 += __shfl_xor(acc2, 32, 64);
        acc3 += __shfl_xor(acc3, 16, 64); acc3 += __shfl_xor(acc3, 32, 64);

        // this lane owns output p = s
        float t01 = (s & 1) ? acc1 : acc0;
        float t23 = (s & 1) ? acc3 : acc2;
        float tot = (s & 2) ? t23 : t01;

        h = 0.9f * h + 0.1f * tot + (float)zc;
        half_t r = (half_t)tanhf(h);
        *(half_t*)(rbase + RSKEW(cur ^ 1, jown)) = r;
        rb[(size_t)(t + 1) * Hv + jown] = r;
        __syncthreads();
        cur ^= 1;
    }
}

// out[bt][o] = sum_j r[bt][j] * wout[j][o]
__global__ __launch_bounds__(256) void out_kernel(
    const half_t* __restrict__ rstore, const uint4* __restrict__ wop4, float* __restrict__ out)
{
    __shared__ uint4 rr[32 * 64];
    const int tid = threadIdx.x;
    const int o = tid & 63, q = tid >> 6;
    const size_t bt0 = (size_t)blockIdx.x * 32;

    for (int idx = tid; idx < 32 * 64; idx += 256)
        rr[idx] = ((const uint4*)rstore)[bt0 * 64 + idx];
    __syncthreads();

    float acc[8] = {0.f, 0.f, 0.f, 0.f, 0.f, 0.f, 0.f, 0.f};
#pragma unroll 8
    for (int g = 0; g < 64; ++g) {
        uint4 wv = wop4[g * 64 + o];
#pragma unroll
        for (int i = 0; i < 8; ++i) {
            uint4 rv = rr[(q + 4 * i) * 64 + g];
            float a = fdot2(wv.x, rv.x, acc[i]);
            a = fdot2(wv.y, rv.y, a);
            a = fdot2(wv.z, rv.z, a);
            acc[i] = fdot2(wv.w, rv.w, a);
        }
    }
#pragma unroll
    for (int i = 0; i < 8; ++i)
        out[(bt0 + q + 4 * i) * Ov + o] = acc[i];
}

// ===================== LEGACY FALLBACK (R1, proven) =====================
__global__ void pack_wrec_k(const float* __restrict__ wrec, unsigned int* __restrict__ wp) {
    int tid = blockIdx.x * 256 + threadIdx.x;
    int k = tid & 3, j = (tid >> 2) & 511, q = tid >> 11;
    int i0 = 8 * q + 2 * k;
    wp[tid] = pack2(wrec[j * Hv + i0], wrec[j * Hv + i0 + 1]);
}
__global__ void pack_wi_k(const float* __restrict__ wi, unsigned int* __restrict__ wp) {
    int tid = blockIdx.x * 256 + threadIdx.x;
    int k = tid & 3, j = (tid >> 2) & 511, q = tid >> 11;
    int i0 = 8 * q + 2 * k;
    wp[tid] = pack2(wi[i0 * Hv + j], wi[(i0 + 1) * Hv + j]);
}
__global__ void pack_wout_k(const float* __restrict__ wout, unsigned int* __restrict__ wp) {
    int tid = blockIdx.x * 256 + threadIdx.x;
    int o = tid & 63, m = tid >> 6;
    wp[tid] = pack2(wout[(2 * m) * Ov + o], wout[(2 * m + 1) * Ov + o]);
}
__global__ __launch_bounds__(512) void rnn_persistent(
    const float* __restrict__ x, const float* __restrict__ noise,
    const float* __restrict__ h0,
    const unsigned int* __restrict__ wrecp,
    const unsigned int* __restrict__ wip,
    const unsigned int* __restrict__ wop,
    float* __restrict__ out)
{
    __shared__ __align__(16) unsigned int s_r[2][256];
    __shared__ __align__(16) unsigned int s_x[64];
    const int tid = threadIdx.x;
    const int b = blockIdx.x;
    const int o = tid >> 3;
    const int g = tid & 7;
    const float* xb = x + (size_t)b * Tv * Iv;
    const float* nb = noise + (size_t)b * Tv * Hv;
    float* ob = out + (size_t)b * Tv * Ov;
    unsigned int wiReg[64];
#pragma unroll
    for (int m = 0; m < 64; ++m)
        wiReg[m] = wip[(((m >> 2) * Hv) + tid) * 4 + (m & 3)];
    unsigned int wo[32];
#pragma unroll
    for (int k = 0; k < 32; ++k)
        wo[k] = wop[(g * 32 + k) * Ov + o];
    float h = h0[tid];
    ((half_t*)&s_r[0][0])[tid] = (half_t)tanhf(h);
    __syncthreads();
    {
        float po = 0.f;
        const uint4* r2 = (const uint4*)&s_r[0][0];
#pragma unroll
        for (int k = 0; k < 8; ++k) {
            uint4 rv = r2[g * 8 + k];
            po = fdot2(wo[4 * k + 0], rv.x, po);
            po = fdot2(wo[4 * k + 1], rv.y, po);
            po = fdot2(wo[4 * k + 2], rv.z, po);
            po = fdot2(wo[4 * k + 3], rv.w, po);
        }
        po += __shfl_xor(po, 1, 64);
        po += __shfl_xor(po, 2, 64);
        po += __shfl_xor(po, 4, 64);
        if (g == 0) ob[o] = po;
    }
    const uint4* wr4 = (const uint4*)wrecp;
    int cur = 0;
    for (int t = 0; t < Tv - 1; ++t) {
        const int nxt = cur ^ 1;
        float nval = nb[t * Hv + tid];
        if (tid < Iv) ((half_t*)&s_x[0])[tid] = (half_t)xb[t * Iv + tid];
        __syncthreads();
        float acc = 0.f;
        const uint4* rr4 = (const uint4*)&s_r[cur][0];
#pragma unroll 8
        for (int q = 0; q < 64; ++q) {
            uint4 w = wr4[q * Hv + tid];
            uint4 r = rr4[q];
            acc = fdot2(w.x, r.x, acc);
            acc = fdot2(w.y, r.y, acc);
            acc = fdot2(w.z, r.z, acc);
            acc = fdot2(w.w, r.w, acc);
        }
        const uint4* xx4 = (const uint4*)&s_x[0];
#pragma unroll
        for (int m = 0; m < 16; ++m) {
            uint4 xv = xx4[m];
            acc = fdot2(wiReg[4 * m + 0], xv.x, acc);
            acc = fdot2(wiReg[4 * m + 1], xv.y, acc);
            acc = fdot2(wiReg[4 * m + 2], xv.z, acc);
            acc = fdot2(wiReg[4 * m + 3], xv.w, acc);
        }
        h = h + 0.0005f * nval + 0.1f * (acc - h);
        ((half_t*)&s_r[nxt][0])[tid] = (half_t)tanhf(h);
        __syncthreads();
        float po = 0.f;
        const uint4* r2 = (const uint4*)&s_r[nxt][0];
#pragma unroll
        for (int k = 0; k < 8; ++k) {
            uint4 rv = r2[g * 8 + k];
            po = fdot2(wo[4 * k + 0], rv.x, po);
            po = fdot2(wo[4 * k + 1], rv.y, po);
            po = fdot2(wo[4 * k + 2], rv.z, po);
            po = fdot2(wo[4 * k + 3], rv.w, po);
        }
        po += __shfl_xor(po, 1, 64);
        po += __shfl_xor(po, 2, 64);
        po += __shfl_xor(po, 4, 64);
        if (g == 0) ob[(t + 1) * Ov + o] = po;
        cur = nxt;
    }
}

// ===================== LAUNCHER =====================
extern "C" void kernel_launch(void* const* d_in, const int* in_sizes, int n_in,
                              void* d_out, int out_size, void* d_ws, size_t ws_size,
                              hipStream_t stream) {
    const float* input = (const float*)d_in[0];
    const float* noise = (const float*)d_in[1];
    const float* wi    = (const float*)d_in[2];
    const float* wrec  = (const float*)d_in[3];
    const float* wout  = (const float*)d_in[4];
    const float* h0    = (const float*)d_in[5];
    float* out = (float*)d_out;

    const size_t Z_OFF  = 0;
    const size_t R_OFF  = Z_OFF + 134217728;
    const size_t WA_OFF = R_OFF + 134217728;
    const size_t WB_OFF = WA_OFF + 368640;
    const size_t WI_OFF = WB_OFF + 155648;
    const size_t WO_OFF = WI_OFF + 131072;
    const size_t NEED   = WO_OFF + 65536;

    if (ws_size >= NEED) {
        unsigned char* ws = (unsigned char*)d_ws;
        half_t*       zg    = (half_t*)(ws + Z_OFF);
        half_t*       rsg   = (half_t*)(ws + R_OFF);
        unsigned int* wrAg  = (unsigned int*)(ws + WA_OFF);
        unsigned int* wBg   = (unsigned int*)(ws + WB_OFF);
        unsigned int* wipg  = (unsigned int*)(ws + WI_OFF);
        uint4*        wop4g = (uint4*)(ws + WO_OFF);

        hipLaunchKernelGGL(pack_wrA4_k, dim3(360), dim3(256), 0, stream, wrec, wrAg);
        hipLaunchKernelGGL(pack_wB4_k,  dim3(152), dim3(256), 0, stream, wrec, wBg);
        hipLaunchKernelGGL(pack_wip_k,  dim3(128), dim3(256), 0, stream, wi, wipg);
        hipLaunchKernelGGL(pack_wop_k,  dim3(16),  dim3(256), 0, stream, wout, wop4g);

        hipLaunchKernelGGL(z_kernel, dim3((Bv * Tv) / 32), dim3(512), 0, stream,
                           input, noise, wipg, zg);

        const int smem = 19 * 512 * 16 + 2 * 1088;   // 157824 B
        hipFuncSetAttribute((const void*)rnn_fast,
                            hipFuncAttributeMaxDynamicSharedMemorySize, smem);
        hipLaunchKernelGGL(rnn_fast, dim3(Bv), dim3(512), smem, stream,
                           wrAg, (const uint4*)wBg, zg, h0, rsg);

        hipLaunchKernelGGL(out_kernel, dim3((Bv * Tv) / 32), dim3(256), 0, stream,
                           rsg, wop4g, out);
    } else {
        unsigned int* wrecp = (unsigned int*)d_ws;
        unsigned int* wip   = wrecp + 64 * 512 * 4;
        unsigned int* wop   = wip   + 16 * 512 * 4;
        hipLaunchKernelGGL(pack_wrec_k, dim3(512), dim3(256), 0, stream, wrec, wrecp);
        hipLaunchKernelGGL(pack_wi_k,   dim3(128), dim3(256), 0, stream, wi, wip);
        hipLaunchKernelGGL(pack_wout_k, dim3(64),  dim3(256), 0, stream, wout, wop);
        hipLaunchKernelGGL(rnn_persistent, dim3(Bv), dim3(512), 0, stream,
                           input, noise, h0, wrecp, wip, wop, out);
    }
}